// Round 3
// baseline (555.736 us; speedup 1.0000x reference)
//
#include <hip/hip_runtime.h>
#include <hip/hip_bf16.h>
#include <stdint.h>

typedef __attribute__((ext_vector_type(4))) float f32x4;
typedef __attribute__((ext_vector_type(16))) float f32x16;
typedef __bf16 bf16x8v __attribute__((ext_vector_type(8)));
typedef __attribute__((ext_vector_type(4))) unsigned int u32x4;

constexpr int NB = 2;
constexpr int NS = 2048;
constexpr int ND = 1024;
constexpr int NH = 16;
constexpr int NDK = 64;

__device__ __forceinline__ void gload16(const void* g, void* l) {
    __builtin_amdgcn_global_load_lds(
        (const __attribute__((address_space(1))) unsigned int*)g,
        (__attribute__((address_space(3))) unsigned int*)l, 16, 0, 0);
}

__device__ __forceinline__ unsigned pack_bf16x2(float lo, float hi) {
    unsigned short a = __builtin_bit_cast(unsigned short, (__bf16)lo);
    unsigned short b = __builtin_bit_cast(unsigned short, (__bf16)hi);
    return (unsigned)a | ((unsigned)b << 16);
}

// ---------------- fp32 -> bf16 convert (x + 4 weights) ----------------
__global__ void __launch_bounds__(256)
cvt_kernel(const float* __restrict__ x, const float* __restrict__ wq,
           const float* __restrict__ wk, const float* __restrict__ wv,
           const float* __restrict__ wo,
           __bf16* __restrict__ xb, __bf16* __restrict__ wqb,
           __bf16* __restrict__ wkb, __bf16* __restrict__ wvb,
           __bf16* __restrict__ wob)
{
    int b = blockIdx.x;
    const float* s; __bf16* d;
    if (b < 2048)      { s = x;  d = xb;            }
    else if (b < 2560) { s = wq; d = wqb; b -= 2048; }
    else if (b < 3072) { s = wk; d = wkb; b -= 2560; }
    else if (b < 3584) { s = wv; d = wvb; b -= 3072; }
    else               { s = wo; d = wob; b -= 3584; }
    const size_t i = ((size_t)b * 256 + threadIdx.x) * 8;
    const f32x4 v0 = *(const f32x4*)(s + i);
    const f32x4 v1 = *(const f32x4*)(s + i + 4);
    bf16x8v o;
#pragma unroll
    for (int j = 0; j < 4; ++j) { o[j] = (__bf16)v0[j]; o[4+j] = (__bf16)v1[j]; }
    *(bf16x8v*)(d + i) = o;
}

// ---------------- fused QKV projection GEMM (m97 structure) ----------------
// 128x128 tile, BK=32, global_load_lds w/ pre-swizzled source.
// __launch_bounds__(256,3): VGPR cap ~170 so acc[4][4] (64 VGPR) stays in
// registers — round-2's (256) default allocated 72 VGPR and spilled acc to
// scratch (1.5 GB HBM writes, 420 us).
__global__ void __launch_bounds__(256, 3)
qkv_kernel(const __bf16* __restrict__ xb,
           const __bf16* __restrict__ wqb, const __bf16* __restrict__ wkb,
           const __bf16* __restrict__ wvb, const int* __restrict__ pos,
           __bf16* __restrict__ qw, __bf16* __restrict__ kw,
           __bf16* __restrict__ vtw)
{
    __shared__ __align__(16) __bf16 a_lds[128 * 32];
    __shared__ __align__(16) __bf16 b_lds[128 * 32];

    const int t = threadIdx.x, w = t >> 6, lane = t & 63;
    const int g = lane >> 4, c = lane & 15;
    const int bm = blockIdx.x, bn = blockIdx.y;
    const int mode = bn >> 3, nblk = bn & 7;
    const __bf16* wsel = (mode == 0) ? wqb : (mode == 1) ? wkb : wvb;
    const int wm = w >> 1, wn = w & 1;

    f32x4 acc[4][4] = {};

    for (int kt = 0; kt < 32; ++kt) {
        __syncthreads();
#pragma unroll
        for (int j = 0; j < 2; ++j) {
            const int G = (w * 2 + j) * 64 + lane;
            const int r = G >> 2, cb = (G & 3) ^ (r & 3);
            gload16(xb   + (size_t)(bm   * 128 + r) * ND + kt * 32 + cb * 8,
                    &a_lds[(w * 2 + j) * 512]);
            gload16(wsel + (size_t)(nblk * 128 + r) * ND + kt * 32 + cb * 8,
                    &b_lds[(w * 2 + j) * 512]);
        }
        __syncthreads();
        bf16x8v af[4], bfr[4];
#pragma unroll
        for (int f = 0; f < 4; ++f) {
            const int ra = wm * 64 + f * 16 + c;
            af[f]  = *(const bf16x8v*)&a_lds[ra * 32 + ((g ^ (ra & 3)) * 8)];
            const int rb = wn * 64 + f * 16 + c;
            bfr[f] = *(const bf16x8v*)&b_lds[rb * 32 + ((g ^ (rb & 3)) * 8)];
        }
#pragma unroll
        for (int fm = 0; fm < 4; ++fm)
#pragma unroll
            for (int fn = 0; fn < 4; ++fn)
                acc[fm][fn] = __builtin_amdgcn_mfma_f32_16x16x32_bf16(
                    af[fm], bfr[fn], acc[fm][fn], 0, 0, 0);
    }

    // epilogue
    const int h_out = nblk * 2 + wn;  // head index (n>>6)
#pragma unroll
    for (int fm = 0; fm < 4; ++fm) {
        const int m0 = bm * 128 + wm * 64 + fm * 16 + g * 4;
        const int bI = m0 >> 11, s0 = m0 & (NS - 1);
#pragma unroll
        for (int fn = 0; fn < 4; ++fn) {
            const int d = fn * 16 + c;  // head-dim
            float vals[4] = {acc[fm][fn][0], acc[fm][fn][1],
                             acc[fm][fn][2], acc[fm][fn][3]};
            if (mode < 2) {
                const float freq = __expf((float)(d & ~1) * (-0.14391156831212787f));
#pragma unroll
                for (int i = 0; i < 4; ++i) {
                    const float ang = (float)pos[(m0 + i) & (NS - 1)] * freq;
                    float sn, cs;
                    sincosf(ang, &sn, &cs);
                    const float mine = vals[i];
                    const float oth = __shfl_xor(mine, 1, 64);
                    vals[i] = (d & 1) ? (oth * sn + mine * cs) : (mine * cs - oth * sn);
                    if (mode == 0) vals[i] *= 0.18033688011112042f;  // 0.125*log2(e)
                }
                __bf16* dq = (mode == 0) ? qw : kw;
#pragma unroll
                for (int i = 0; i < 4; ++i)
                    dq[(((size_t)bI * NH + h_out) * NS + (s0 + i)) * NDK + d] =
                        (__bf16)vals[i];
            } else {
                ushort4 pk;
                pk.x = __builtin_bit_cast(unsigned short, (__bf16)vals[0]);
                pk.y = __builtin_bit_cast(unsigned short, (__bf16)vals[1]);
                pk.z = __builtin_bit_cast(unsigned short, (__bf16)vals[2]);
                pk.w = __builtin_bit_cast(unsigned short, (__bf16)vals[3]);
                *(ushort4*)&vtw[(((size_t)bI * NH + h_out) * NDK + d) * NS + s0] = pk;
            }
        }
    }
}

// ---------------- flash attention, swapped-operand 32x32 structure ----------------
// q,k: [b*16+h][s][64] bf16 (q pre-scaled by 0.125*log2e); vt: [b*16+h][d][s].
// 8 waves x QBLK=32, KVBLK=64. S^T = mfma(K,Q); O^T = mfma(V^T,P^T); all softmax
// state lane-local (lane = (q-col c, half h)). o: [b*S][1024] bf16 token-major.
__global__ void __launch_bounds__(512, 4)
attn_kernel(const __bf16* __restrict__ q, const __bf16* __restrict__ k,
            const __bf16* __restrict__ vt, __bf16* __restrict__ o)
{
    __shared__ __align__(16) __bf16 k_lds[64 * 68];
    __shared__ __align__(16) __bf16 vt_lds[64 * 68];
    __shared__ __align__(16) __bf16 o_lds[8][32 * 72];

    const int t = threadIdx.x, w = t >> 6, lane = t & 63;
    const int c = lane & 31, h = lane >> 5;
    const int bid = blockIdx.x;
    const int qt = 7 - (bid >> 6);   // heavy tiles dispatched first
    const int bh = bid & 63;
    const size_t base = (size_t)bh * NS * NDK;
    const int q0 = qt * 256 + w * 32;
    const int kd_w   = (q0 + 31) >> 6;
    const int kd_blk = 4 * qt + 3;

    // Q B-frags: lane (c,h) holds Q[q0+c][16ds+8h+j]
    bf16x8v qf[4];
#pragma unroll
    for (int ds = 0; ds < 4; ++ds)
        qf[ds] = *(const bf16x8v*)(q + base + (size_t)(q0 + c) * NDK + ds * 16 + h * 8);

    float mrow = -3e38f, lrow = 0.f;
    f32x16 oa0 = {}, oa1 = {};

    for (int kt = 0; kt <= kd_blk; ++kt) {
        __syncthreads();
        {   // stage K tile [k][d] and V^T tile [d][k], granule-XOR swizzled
            const int r = t >> 3, cb = t & 7, cbx = (cb ^ (r & 7)) * 8;
            *(bf16x8v*)&k_lds[r * 68 + cbx] =
                *(const bf16x8v*)(k + base + (size_t)(kt * 64 + r) * NDK + cb * 8);
            *(bf16x8v*)&vt_lds[r * 68 + cbx] =
                *(const bf16x8v*)(vt + base + (size_t)r * NS + kt * 64 + cb * 8);
        }
        __syncthreads();
        if (kt > kd_w) continue;  // no barrier below -> counts stay matched

        // S^T = K Q^T : D col = q (lane&31), row = k-local
        f32x16 st0 = {}, st1 = {};
#pragma unroll
        for (int ds = 0; ds < 4; ++ds) {
            const int cbr = ((2 * ds + h) ^ (c & 7)) * 8;
            const bf16x8v k0 = *(const bf16x8v*)&k_lds[c * 68 + cbr];
            const bf16x8v k1 = *(const bf16x8v*)&k_lds[(32 + c) * 68 + cbr];
            st0 = __builtin_amdgcn_mfma_f32_32x32x16_bf16(k0, qf[ds], st0, 0, 0, 0);
            st1 = __builtin_amdgcn_mfma_f32_32x32x16_bf16(k1, qf[ds], st1, 0, 0, 0);
        }

        if (kt == kd_w) {  // causal mask on the diagonal tile
            const int kb = kt * 64, qg = q0 + c;
#pragma unroll
            for (int r = 0; r < 16; ++r) {
                const int krow = (r & 3) + 8 * (r >> 2) + 4 * h;
                if (kb + krow > qg)      st0[r] = -3e38f;
                if (kb + 32 + krow > qg) st1[r] = -3e38f;
            }
        }

        // online softmax (log2 domain; scale folded into Q)
        float mt = st0[0];
#pragma unroll
        for (int r = 1; r < 16; ++r) mt = fmaxf(mt, st0[r]);
#pragma unroll
        for (int r = 0; r < 16; ++r) mt = fmaxf(mt, st1[r]);
        mt = fmaxf(mt, __shfl_xor(mt, 32, 64));
        const float mn = fmaxf(mrow, mt);
        const float al = exp2f(mrow - mn);
        mrow = mn;
        float rs = 0.f;
#pragma unroll
        for (int r = 0; r < 16; ++r) { st0[r] = exp2f(st0[r] - mn); rs += st0[r]; }
#pragma unroll
        for (int r = 0; r < 16; ++r) { st1[r] = exp2f(st1[r] - mn); rs += st1[r]; }
        rs += __shfl_xor(rs, 32, 64);
        lrow = lrow * al + rs;
#pragma unroll
        for (int r = 0; r < 16; ++r) { oa0[r] *= al; oa1[r] *= al; }

        // pack P^T to bf16 pairs (adjacent regs = adjacent k)
        unsigned pw0[8], pw1[8];
#pragma unroll
        for (int r2 = 0; r2 < 8; ++r2) {
            pw0[r2] = pack_bf16x2(st0[2 * r2], st0[2 * r2 + 1]);
            pw1[r2] = pack_bf16x2(st1[2 * r2], st1[2 * r2 + 1]);
        }

        // O^T += V^T P^T : build P B-frag (2 shuffles/step), read V^T A-frag
#define PV_STEP(PW, T, S)  {                                                  \
        const unsigned s0_ = h ? PW[4*(T)+0] : PW[4*(T)+2];                   \
        const unsigned s1_ = h ? PW[4*(T)+1] : PW[4*(T)+3];                   \
        const unsigned g0_ = (unsigned)__shfl_xor((int)s0_, 32, 64);          \
        const unsigned g1_ = (unsigned)__shfl_xor((int)s1_, 32, 64);          \
        const u32x4 pu = { h ? g0_ : PW[4*(T)+0], h ? g1_ : PW[4*(T)+1],      \
                           h ? PW[4*(T)+2] : g0_, h ? PW[4*(T)+3] : g1_ };    \
        const bf16x8v pf = __builtin_bit_cast(bf16x8v, pu);                   \
        const int cbv = ((2*(S) + h) ^ (c & 7)) * 8;                          \
        const bf16x8v v0_ = *(const bf16x8v*)&vt_lds[c * 68 + cbv];           \
        const bf16x8v v1_ = *(const bf16x8v*)&vt_lds[(32 + c) * 68 + cbv];    \
        oa0 = __builtin_amdgcn_mfma_f32_32x32x16_bf16(v0_, pf, oa0, 0, 0, 0); \
        oa1 = __builtin_amdgcn_mfma_f32_32x32x16_bf16(v1_, pf, oa1, 0, 0, 0); }

        PV_STEP(pw0, 0, 0)
        PV_STEP(pw0, 1, 1)
        PV_STEP(pw1, 0, 2)
        PV_STEP(pw1, 1, 3)
#undef PV_STEP
    }

    // epilogue: O^T[d][q=c]/l -> per-wave LDS transpose -> coalesced store
    const float inv = 1.f / lrow;
#pragma unroll
    for (int r = 0; r < 16; ++r) {
        const int crow = (r & 3) + 8 * (r >> 2) + 4 * h;
        o_lds[w][c * 72 + crow]      = (__bf16)(oa0[r] * inv);
        o_lds[w][c * 72 + 32 + crow] = (__bf16)(oa1[r] * inv);
    }
    const int bI = bh >> 4, hh = bh & 15;
    const int qr0 = lane >> 3, cb8 = lane & 7;
#pragma unroll
    for (int mm = 0; mm < 4; ++mm) {
        const int qr = qr0 + 8 * mm;
        const bf16x8v vv = *(const bf16x8v*)&o_lds[w][qr * 72 + cb8 * 8];
        *(bf16x8v*)(o + ((size_t)(bI * NS + q0 + qr)) * ND + hh * NDK + cb8 * 8) = vv;
    }
}

// ---------------- output projection (m97 structure), fp32 out ----------------
__global__ void __launch_bounds__(256, 3)
oproj_kernel(const __bf16* __restrict__ a, const __bf16* __restrict__ wob,
             float* __restrict__ out)
{
    __shared__ __align__(16) __bf16 a_lds[128 * 32];
    __shared__ __align__(16) __bf16 b_lds[128 * 32];

    const int t = threadIdx.x, w = t >> 6, lane = t & 63;
    const int g = lane >> 4, c = lane & 15;
    const int bm = blockIdx.x, bn = blockIdx.y;
    const int wm = w >> 1, wn = w & 1;

    f32x4 acc[4][4] = {};

    for (int kt = 0; kt < 32; ++kt) {
        __syncthreads();
#pragma unroll
        for (int j = 0; j < 2; ++j) {
            const int G = (w * 2 + j) * 64 + lane;
            const int r = G >> 2, cb = (G & 3) ^ (r & 3);
            gload16(a   + (size_t)(bm * 128 + r) * ND + kt * 32 + cb * 8,
                    &a_lds[(w * 2 + j) * 512]);
            gload16(wob + (size_t)(bn * 128 + r) * ND + kt * 32 + cb * 8,
                    &b_lds[(w * 2 + j) * 512]);
        }
        __syncthreads();
        bf16x8v af[4], bfr[4];
#pragma unroll
        for (int f = 0; f < 4; ++f) {
            const int ra = wm * 64 + f * 16 + c;
            af[f]  = *(const bf16x8v*)&a_lds[ra * 32 + ((g ^ (ra & 3)) * 8)];
            const int rb = wn * 64 + f * 16 + c;
            bfr[f] = *(const bf16x8v*)&b_lds[rb * 32 + ((g ^ (rb & 3)) * 8)];
        }
#pragma unroll
        for (int fm = 0; fm < 4; ++fm)
#pragma unroll
            for (int fn = 0; fn < 4; ++fn)
                acc[fm][fn] = __builtin_amdgcn_mfma_f32_16x16x32_bf16(
                    af[fm], bfr[fn], acc[fm][fn], 0, 0, 0);
    }

#pragma unroll
    for (int fm = 0; fm < 4; ++fm) {
        const int m0 = bm * 128 + wm * 64 + fm * 16 + g * 4;
#pragma unroll
        for (int fn = 0; fn < 4; ++fn) {
            const int n = bn * 128 + wn * 64 + fn * 16 + c;
#pragma unroll
            for (int i = 0; i < 4; ++i)
                out[(size_t)(m0 + i) * ND + n] = acc[fm][fn][i];
        }
    }
}

extern "C" void kernel_launch(void* const* d_in, const int* in_sizes, int n_in,
                              void* d_out, int out_size, void* d_ws, size_t ws_size,
                              hipStream_t stream)
{
    const float* x  = (const float*)d_in[0];
    const float* wq = (const float*)d_in[1];
    const float* wk = (const float*)d_in[2];
    const float* wv = (const float*)d_in[3];
    const float* wo = (const float*)d_in[4];
    const int*  pos = (const int*)d_in[5];
    float* out = (float*)d_out;
    (void)in_sizes; (void)n_in; (void)out_size; (void)ws_size;

    const size_t xel = (size_t)NB * NS * ND;   // 4.2M
    const size_t wel = (size_t)ND * ND;        // 1.05M
    __bf16* xb  = (__bf16*)d_ws;
    __bf16* wqb = xb  + xel;
    __bf16* wkb = wqb + wel;
    __bf16* wvb = wkb + wel;
    __bf16* wob = wvb + wel;
    __bf16* qw  = wob + wel;
    __bf16* kw  = qw  + xel;
    __bf16* vtw = kw  + xel;
    __bf16* aw  = vtw + xel;

    cvt_kernel<<<4096, 256, 0, stream>>>(x, wq, wk, wv, wo, xb, wqb, wkb, wvb, wob);

    dim3 qg(32, 24);  // 32 m-tiles x (8 n-tiles x {Q,K,V})
    qkv_kernel<<<qg, 256, 0, stream>>>(xb, wqb, wkb, wvb, pos, qw, kw, vtw);

    attn_kernel<<<512, 512, 0, stream>>>(qw, kw, vtw, aw);

    dim3 og(32, 8);
    oproj_kernel<<<og, 256, 0, stream>>>(aw, wob, out);
}

// Round 4
// 159.103 us; speedup vs baseline: 3.4929x; 3.4929x over previous
//
#include <hip/hip_runtime.h>
#include <hip/hip_bf16.h>
#include <stdint.h>

typedef __attribute__((ext_vector_type(4))) float f32x4;
typedef __attribute__((ext_vector_type(16))) float f32x16;
typedef __bf16 bf16x8v __attribute__((ext_vector_type(8)));
typedef __attribute__((ext_vector_type(4))) unsigned int u32x4;

constexpr int NB = 2;
constexpr int NS = 2048;
constexpr int ND = 1024;
constexpr int NH = 16;
constexpr int NDK = 64;

__device__ __forceinline__ void gload16(const void* g, void* l) {
    __builtin_amdgcn_global_load_lds(
        (const __attribute__((address_space(1))) unsigned int*)g,
        (__attribute__((address_space(3))) unsigned int*)l, 16, 0, 0);
}

__device__ __forceinline__ unsigned pack_bf16x2(float lo, float hi) {
    unsigned short a = __builtin_bit_cast(unsigned short, (__bf16)lo);
    unsigned short b = __builtin_bit_cast(unsigned short, (__bf16)hi);
    return (unsigned)a | ((unsigned)b << 16);
}

// ---------------- fp32 -> bf16 convert (x + 4 weights) ----------------
__global__ void __launch_bounds__(256)
cvt_kernel(const float* __restrict__ x, const float* __restrict__ wq,
           const float* __restrict__ wk, const float* __restrict__ wv,
           const float* __restrict__ wo,
           __bf16* __restrict__ xb, __bf16* __restrict__ wqb,
           __bf16* __restrict__ wkb, __bf16* __restrict__ wvb,
           __bf16* __restrict__ wob)
{
    int b = blockIdx.x;
    const float* s; __bf16* d;
    if (b < 2048)      { s = x;  d = xb;            }
    else if (b < 2560) { s = wq; d = wqb; b -= 2048; }
    else if (b < 3072) { s = wk; d = wkb; b -= 2560; }
    else if (b < 3584) { s = wv; d = wvb; b -= 3072; }
    else               { s = wo; d = wob; b -= 3584; }
    const size_t i = ((size_t)b * 256 + threadIdx.x) * 8;
    const f32x4 v0 = *(const f32x4*)(s + i);
    const f32x4 v1 = *(const f32x4*)(s + i + 4);
    bf16x8v o;
#pragma unroll
    for (int j = 0; j < 4; ++j) { o[j] = (__bf16)v0[j]; o[4+j] = (__bf16)v1[j]; }
    *(bf16x8v*)(d + i) = o;
}

// ---------------- RoPE cos/sin tables: [s][p] p=0..31 ----------------
__global__ void __launch_bounds__(256)
rope_tab_kernel(const int* __restrict__ pos, float* __restrict__ cos_t,
                float* __restrict__ sin_t)
{
    const int idx = blockIdx.x * 256 + threadIdx.x;  // 65536 = 2048*32
    const int s = idx >> 5, p = idx & 31;
    const float freq = __expf((float)p * (-0.28782313662425572f));  // ln(1e4)/32
    const float ang = (float)pos[s] * freq;
    float sn, cs;
    sincosf(ang, &sn, &cs);
    cos_t[idx] = cs;
    sin_t[idx] = sn;
}

// ---- shared GEMM epilogue piece (RoPE-from-table or V^T store), no calls ----
__device__ __forceinline__ void epi_one(
    f32x4 a, int fm, int fn, int bm, int wm, int g, int c, int mode, int h_out,
    const float* __restrict__ cos_t, const float* __restrict__ sin_t,
    __bf16* __restrict__ qw, __bf16* __restrict__ kw, __bf16* __restrict__ vtw)
{
    const int m0 = bm * 128 + wm * 64 + fm * 16 + g * 4;
    const int bI = m0 >> 11, s0 = m0 & (NS - 1);
    const int d = fn * 16 + c;
    float v0 = a[0], v1 = a[1], v2 = a[2], v3 = a[3];
    if (mode < 2) {
        const int p = d >> 1;
        const bool odd = (d & 1);
        const float sc = (mode == 0) ? 0.18033688011112042f : 1.0f;  // 0.125*log2e
#define ROPE1(V, I)                                                        \
        {                                                                  \
            const float cs = cos_t[(s0 + (I)) * 32 + p];                   \
            const float sn = sin_t[(s0 + (I)) * 32 + p];                   \
            const float oth = __shfl_xor(V, 1, 64);                        \
            V = (odd ? (oth * sn + V * cs) : (V * cs - oth * sn)) * sc;    \
        }
        ROPE1(v0, 0) ROPE1(v1, 1) ROPE1(v2, 2) ROPE1(v3, 3)
#undef ROPE1
        __bf16* dq = (mode == 0) ? qw : kw;
        __bf16* b = dq + (((size_t)bI * NH + h_out) * NS + s0) * NDK + d;
        b[0] = (__bf16)v0; b[NDK] = (__bf16)v1;
        b[2 * NDK] = (__bf16)v2; b[3 * NDK] = (__bf16)v3;
    } else {
        ushort4 pk;
        pk.x = __builtin_bit_cast(unsigned short, (__bf16)v0);
        pk.y = __builtin_bit_cast(unsigned short, (__bf16)v1);
        pk.z = __builtin_bit_cast(unsigned short, (__bf16)v2);
        pk.w = __builtin_bit_cast(unsigned short, (__bf16)v3);
        *(ushort4*)&vtw[(((size_t)bI * NH + h_out) * NDK + d) * NS + s0] = pk;
    }
}

// ---------------- fused QKV projection GEMM (m97 structure) ----------------
// NAMED accumulators/fragments only — round-2/3 array versions were demoted to
// scratch (SROA failure: 8 KB/thread/loop => 1.6 GB HBM writes, 455 us).
__global__ void __launch_bounds__(256, 2)
qkv_kernel(const __bf16* __restrict__ xb,
           const __bf16* __restrict__ wqb, const __bf16* __restrict__ wkb,
           const __bf16* __restrict__ wvb,
           const float* __restrict__ cos_t, const float* __restrict__ sin_t,
           __bf16* __restrict__ qw, __bf16* __restrict__ kw,
           __bf16* __restrict__ vtw)
{
    __shared__ __align__(16) __bf16 a_lds[128 * 32];
    __shared__ __align__(16) __bf16 b_lds[128 * 32];

    const int t = threadIdx.x, w = t >> 6, lane = t & 63;
    const int g = lane >> 4, c = lane & 15;
    const int bm = blockIdx.x, bn = blockIdx.y;
    const int mode = bn >> 3, nblk = bn & 7;
    const __bf16* wsel = (mode == 0) ? wqb : (mode == 1) ? wkb : wvb;
    const int wm = w >> 1, wn = w & 1;

    f32x4 acc00 = {}, acc01 = {}, acc02 = {}, acc03 = {};
    f32x4 acc10 = {}, acc11 = {}, acc12 = {}, acc13 = {};
    f32x4 acc20 = {}, acc21 = {}, acc22 = {}, acc23 = {};
    f32x4 acc30 = {}, acc31 = {}, acc32 = {}, acc33 = {};

    const int sl = (g ^ (c & 3)) * 8;  // XOR slot constant across f (16|ra-base)
    const __bf16* arow = &a_lds[(wm * 64 + c) * 32 + sl];
    const __bf16* brow = &b_lds[(wn * 64 + c) * 32 + sl];

    for (int kt = 0; kt < 32; ++kt) {
        __syncthreads();
#pragma unroll
        for (int j = 0; j < 2; ++j) {
            const int G = (w * 2 + j) * 64 + lane;
            const int r = G >> 2, cb = (G & 3) ^ (r & 3);
            gload16(xb   + (size_t)(bm   * 128 + r) * ND + kt * 32 + cb * 8,
                    &a_lds[(w * 2 + j) * 512]);
            gload16(wsel + (size_t)(nblk * 128 + r) * ND + kt * 32 + cb * 8,
                    &b_lds[(w * 2 + j) * 512]);
        }
        __syncthreads();
        const bf16x8v af0 = *(const bf16x8v*)(arow);
        const bf16x8v af1 = *(const bf16x8v*)(arow + 512);
        const bf16x8v af2 = *(const bf16x8v*)(arow + 1024);
        const bf16x8v af3 = *(const bf16x8v*)(arow + 1536);
        const bf16x8v bf0 = *(const bf16x8v*)(brow);
        const bf16x8v bf1 = *(const bf16x8v*)(brow + 512);
        const bf16x8v bf2 = *(const bf16x8v*)(brow + 1024);
        const bf16x8v bf3 = *(const bf16x8v*)(brow + 1536);
#define MM(FM, FN) acc##FM##FN = __builtin_amdgcn_mfma_f32_16x16x32_bf16( \
        af##FM, bf##FN, acc##FM##FN, 0, 0, 0);
        MM(0,0) MM(0,1) MM(0,2) MM(0,3)
        MM(1,0) MM(1,1) MM(1,2) MM(1,3)
        MM(2,0) MM(2,1) MM(2,2) MM(2,3)
        MM(3,0) MM(3,1) MM(3,2) MM(3,3)
#undef MM
    }

    const int h_out = nblk * 2 + wn;
#define EP(FM, FN) epi_one(acc##FM##FN, FM, FN, bm, wm, g, c, mode, h_out, \
                           cos_t, sin_t, qw, kw, vtw);
    EP(0,0) EP(0,1) EP(0,2) EP(0,3)
    EP(1,0) EP(1,1) EP(1,2) EP(1,3)
    EP(2,0) EP(2,1) EP(2,2) EP(2,3)
    EP(3,0) EP(3,1) EP(3,2) EP(3,3)
#undef EP
}

// ---------------- flash attention, swapped-operand 32x32 structure ----------------
// q,k: [b*16+h][s][64] bf16 (q pre-scaled by 0.125*log2e); vt: [b*16+h][d][s].
// 8 waves x QBLK=32, KVBLK=64. S^T = mfma(K,Q); O^T = mfma(V^T,P^T); all softmax
// state lane-local. o: [b*S][1024] bf16 token-major.  (unchanged from round 2)
__global__ void __launch_bounds__(512, 4)
attn_kernel(const __bf16* __restrict__ q, const __bf16* __restrict__ k,
            const __bf16* __restrict__ vt, __bf16* __restrict__ o)
{
    __shared__ __align__(16) __bf16 k_lds[64 * 68];
    __shared__ __align__(16) __bf16 vt_lds[64 * 68];
    __shared__ __align__(16) __bf16 o_lds[8][32 * 72];

    const int t = threadIdx.x, w = t >> 6, lane = t & 63;
    const int c = lane & 31, h = lane >> 5;
    const int bid = blockIdx.x;
    const int qt = 7 - (bid >> 6);   // heavy tiles dispatched first
    const int bh = bid & 63;
    const size_t base = (size_t)bh * NS * NDK;
    const int q0 = qt * 256 + w * 32;
    const int kd_w   = (q0 + 31) >> 6;
    const int kd_blk = 4 * qt + 3;

    bf16x8v qf0, qf1, qf2, qf3;
    {
        const __bf16* qp = q + base + (size_t)(q0 + c) * NDK + h * 8;
        qf0 = *(const bf16x8v*)(qp);
        qf1 = *(const bf16x8v*)(qp + 16);
        qf2 = *(const bf16x8v*)(qp + 32);
        qf3 = *(const bf16x8v*)(qp + 48);
    }

    float mrow = -3e38f, lrow = 0.f;
    f32x16 oa0 = {}, oa1 = {};

    for (int kt = 0; kt <= kd_blk; ++kt) {
        __syncthreads();
        {   // stage K tile [k][d] and V^T tile [d][k], granule-XOR swizzled
            const int r = t >> 3, cb = t & 7, cbx = (cb ^ (r & 7)) * 8;
            *(bf16x8v*)&k_lds[r * 68 + cbx] =
                *(const bf16x8v*)(k + base + (size_t)(kt * 64 + r) * NDK + cb * 8);
            *(bf16x8v*)&vt_lds[r * 68 + cbx] =
                *(const bf16x8v*)(vt + base + (size_t)r * NS + kt * 64 + cb * 8);
        }
        __syncthreads();
        if (kt > kd_w) continue;  // no barrier below -> counts stay matched

        // S^T = K Q^T : D col = q (lane&31), row = k-local
        f32x16 st0 = {}, st1 = {};
#define QK(DS, QF)                                                            \
        {                                                                     \
            const int cbr = ((2 * (DS) + h) ^ (c & 7)) * 8;                   \
            const bf16x8v k0 = *(const bf16x8v*)&k_lds[c * 68 + cbr];         \
            const bf16x8v k1 = *(const bf16x8v*)&k_lds[(32 + c) * 68 + cbr];  \
            st0 = __builtin_amdgcn_mfma_f32_32x32x16_bf16(k0, QF, st0, 0, 0, 0); \
            st1 = __builtin_amdgcn_mfma_f32_32x32x16_bf16(k1, QF, st1, 0, 0, 0); \
        }
        QK(0, qf0) QK(1, qf1) QK(2, qf2) QK(3, qf3)
#undef QK

        if (kt == kd_w) {  // causal mask on the diagonal tile
            const int kb = kt * 64, qg = q0 + c;
#pragma unroll
            for (int r = 0; r < 16; ++r) {
                const int krow = (r & 3) + 8 * (r >> 2) + 4 * h;
                if (kb + krow > qg)      st0[r] = -3e38f;
                if (kb + 32 + krow > qg) st1[r] = -3e38f;
            }
        }

        // online softmax (log2 domain; scale folded into Q)
        float mt = st0[0];
#pragma unroll
        for (int r = 1; r < 16; ++r) mt = fmaxf(mt, st0[r]);
#pragma unroll
        for (int r = 0; r < 16; ++r) mt = fmaxf(mt, st1[r]);
        mt = fmaxf(mt, __shfl_xor(mt, 32, 64));
        const float mn = fmaxf(mrow, mt);
        const float al = exp2f(mrow - mn);
        mrow = mn;
        float rs = 0.f;
#pragma unroll
        for (int r = 0; r < 16; ++r) { st0[r] = exp2f(st0[r] - mn); rs += st0[r]; }
#pragma unroll
        for (int r = 0; r < 16; ++r) { st1[r] = exp2f(st1[r] - mn); rs += st1[r]; }
        rs += __shfl_xor(rs, 32, 64);
        lrow = lrow * al + rs;
#pragma unroll
        for (int r = 0; r < 16; ++r) { oa0[r] *= al; oa1[r] *= al; }

        // pack P^T to bf16 pairs; O^T += V^T P^T (2 shuffles/step)
#define PV_STEP(ST, T, S)  {                                                  \
        const unsigned w0_ = pack_bf16x2(ST[8*(T)+0], ST[8*(T)+1]);           \
        const unsigned w1_ = pack_bf16x2(ST[8*(T)+2], ST[8*(T)+3]);           \
        const unsigned w2_ = pack_bf16x2(ST[8*(T)+4], ST[8*(T)+5]);           \
        const unsigned w3_ = pack_bf16x2(ST[8*(T)+6], ST[8*(T)+7]);           \
        const unsigned s0_ = h ? w0_ : w2_;                                   \
        const unsigned s1_ = h ? w1_ : w3_;                                   \
        const unsigned g0_ = (unsigned)__shfl_xor((int)s0_, 32, 64);          \
        const unsigned g1_ = (unsigned)__shfl_xor((int)s1_, 32, 64);          \
        const u32x4 pu = { h ? g0_ : w0_, h ? g1_ : w1_,                      \
                           h ? w2_ : g0_, h ? w3_ : g1_ };                    \
        const bf16x8v pf = __builtin_bit_cast(bf16x8v, pu);                   \
        const int cbv = ((2*(S) + h) ^ (c & 7)) * 8;                          \
        const bf16x8v v0_ = *(const bf16x8v*)&vt_lds[c * 68 + cbv];           \
        const bf16x8v v1_ = *(const bf16x8v*)&vt_lds[(32 + c) * 68 + cbv];    \
        oa0 = __builtin_amdgcn_mfma_f32_32x32x16_bf16(v0_, pf, oa0, 0, 0, 0); \
        oa1 = __builtin_amdgcn_mfma_f32_32x32x16_bf16(v1_, pf, oa1, 0, 0, 0); }

        PV_STEP(st0, 0, 0)
        PV_STEP(st0, 1, 1)
        PV_STEP(st1, 0, 2)
        PV_STEP(st1, 1, 3)
#undef PV_STEP
    }

    // epilogue: O^T[d][q=c]/l -> per-wave LDS transpose -> coalesced store
    const float inv = 1.f / lrow;
#pragma unroll
    for (int r = 0; r < 16; ++r) {
        const int crow = (r & 3) + 8 * (r >> 2) + 4 * h;
        o_lds[w][c * 72 + crow]      = (__bf16)(oa0[r] * inv);
        o_lds[w][c * 72 + 32 + crow] = (__bf16)(oa1[r] * inv);
    }
    const int bI = bh >> 4, hh = bh & 15;
    const int qr0 = lane >> 3, cb8 = lane & 7;
#pragma unroll
    for (int mm = 0; mm < 4; ++mm) {
        const int qr = qr0 + 8 * mm;
        const bf16x8v vv = *(const bf16x8v*)&o_lds[w][qr * 72 + cb8 * 8];
        *(bf16x8v*)(o + ((size_t)(bI * NS + q0 + qr)) * ND + hh * NDK + cb8 * 8) = vv;
    }
}

// ---------------- output projection (named-reg m97 structure), fp32 out ----------------
__global__ void __launch_bounds__(256, 2)
oproj_kernel(const __bf16* __restrict__ a, const __bf16* __restrict__ wob,
             float* __restrict__ out)
{
    __shared__ __align__(16) __bf16 a_lds[128 * 32];
    __shared__ __align__(16) __bf16 b_lds[128 * 32];

    const int t = threadIdx.x, w = t >> 6, lane = t & 63;
    const int g = lane >> 4, c = lane & 15;
    const int bm = blockIdx.x, bn = blockIdx.y;
    const int wm = w >> 1, wn = w & 1;

    f32x4 acc00 = {}, acc01 = {}, acc02 = {}, acc03 = {};
    f32x4 acc10 = {}, acc11 = {}, acc12 = {}, acc13 = {};
    f32x4 acc20 = {}, acc21 = {}, acc22 = {}, acc23 = {};
    f32x4 acc30 = {}, acc31 = {}, acc32 = {}, acc33 = {};

    const int sl = (g ^ (c & 3)) * 8;
    const __bf16* arow = &a_lds[(wm * 64 + c) * 32 + sl];
    const __bf16* brow = &b_lds[(wn * 64 + c) * 32 + sl];

    for (int kt = 0; kt < 32; ++kt) {
        __syncthreads();
#pragma unroll
        for (int j = 0; j < 2; ++j) {
            const int G = (w * 2 + j) * 64 + lane;
            const int r = G >> 2, cb = (G & 3) ^ (r & 3);
            gload16(a   + (size_t)(bm * 128 + r) * ND + kt * 32 + cb * 8,
                    &a_lds[(w * 2 + j) * 512]);
            gload16(wob + (size_t)(bn * 128 + r) * ND + kt * 32 + cb * 8,
                    &b_lds[(w * 2 + j) * 512]);
        }
        __syncthreads();
        const bf16x8v af0 = *(const bf16x8v*)(arow);
        const bf16x8v af1 = *(const bf16x8v*)(arow + 512);
        const bf16x8v af2 = *(const bf16x8v*)(arow + 1024);
        const bf16x8v af3 = *(const bf16x8v*)(arow + 1536);
        const bf16x8v bf0 = *(const bf16x8v*)(brow);
        const bf16x8v bf1 = *(const bf16x8v*)(brow + 512);
        const bf16x8v bf2 = *(const bf16x8v*)(brow + 1024);
        const bf16x8v bf3 = *(const bf16x8v*)(brow + 1536);
#define MM(FM, FN) acc##FM##FN = __builtin_amdgcn_mfma_f32_16x16x32_bf16( \
        af##FM, bf##FN, acc##FM##FN, 0, 0, 0);
        MM(0,0) MM(0,1) MM(0,2) MM(0,3)
        MM(1,0) MM(1,1) MM(1,2) MM(1,3)
        MM(2,0) MM(2,1) MM(2,2) MM(2,3)
        MM(3,0) MM(3,1) MM(3,2) MM(3,3)
#undef MM
    }

#define EPO(FM, FN, A)                                                     \
    {                                                                      \
        const int m0 = bm * 128 + wm * 64 + (FM) * 16 + g * 4;             \
        const int n = bn * 128 + wn * 64 + (FN) * 16 + c;                  \
        out[(size_t)(m0 + 0) * ND + n] = A[0];                             \
        out[(size_t)(m0 + 1) * ND + n] = A[1];                             \
        out[(size_t)(m0 + 2) * ND + n] = A[2];                             \
        out[(size_t)(m0 + 3) * ND + n] = A[3];                             \
    }
    EPO(0,0,acc00) EPO(0,1,acc01) EPO(0,2,acc02) EPO(0,3,acc03)
    EPO(1,0,acc10) EPO(1,1,acc11) EPO(1,2,acc12) EPO(1,3,acc13)
    EPO(2,0,acc20) EPO(2,1,acc21) EPO(2,2,acc22) EPO(2,3,acc23)
    EPO(3,0,acc30) EPO(3,1,acc31) EPO(3,2,acc32) EPO(3,3,acc33)
#undef EPO
}

extern "C" void kernel_launch(void* const* d_in, const int* in_sizes, int n_in,
                              void* d_out, int out_size, void* d_ws, size_t ws_size,
                              hipStream_t stream)
{
    const float* x  = (const float*)d_in[0];
    const float* wq = (const float*)d_in[1];
    const float* wk = (const float*)d_in[2];
    const float* wv = (const float*)d_in[3];
    const float* wo = (const float*)d_in[4];
    const int*  pos = (const int*)d_in[5];
    float* out = (float*)d_out;
    (void)in_sizes; (void)n_in; (void)out_size; (void)ws_size;

    float* cos_t = (float*)d_ws;
    float* sin_t = cos_t + NS * 32;

    const size_t xel = (size_t)NB * NS * ND;   // 4.2M
    const size_t wel = (size_t)ND * ND;        // 1.05M
    __bf16* xb  = (__bf16*)(sin_t + NS * 32);
    __bf16* wqb = xb  + xel;
    __bf16* wkb = wqb + wel;
    __bf16* wvb = wkb + wel;
    __bf16* wob = wvb + wel;
    __bf16* qw  = wob + wel;
    __bf16* kw  = qw  + xel;
    __bf16* vtw = kw  + xel;
    __bf16* aw  = vtw + xel;

    cvt_kernel<<<4096, 256, 0, stream>>>(x, wq, wk, wv, wo, xb, wqb, wkb, wvb, wob);
    rope_tab_kernel<<<NS * 32 / 256, 256, 0, stream>>>(pos, cos_t, sin_t);

    dim3 qg(32, 24);  // 32 m-tiles x (8 n-tiles x {Q,K,V})
    qkv_kernel<<<qg, 256, 0, stream>>>(xb, wqb, wkb, wvb, cos_t, sin_t, qw, kw, vtw);

    attn_kernel<<<512, 512, 0, stream>>>(qw, kw, vtw, aw);

    dim3 og(32, 8);
    oproj_kernel<<<og, 256, 0, stream>>>(aw, wob, out);
}